// Round 4
// baseline (157.763 us; speedup 1.0000x reference)
//
#include <hip/hip_runtime.h>
#include <hip/hip_bf16.h>

#define S_LEN 2048
#define DK 128
#define DV 128
#define BN 64     // KV rows per tile
#define NT 32     // KV tiles per batch
#define LDP 72    // LDS P row stride (bf16)
#define TILE_B 16384                        // bytes per staged tile (64x128 bf16)
#define VWS_OFF ((size_t)16 * NT * TILE_B)  // 8.39 MB
#define WS_NEED ((size_t)2 * 16 * NT * TILE_B)

typedef __attribute__((ext_vector_type(8))) short s16x8;
typedef __attribute__((ext_vector_type(4))) short s16x4;
typedef __attribute__((ext_vector_type(8))) __bf16 bf16x8;
typedef __attribute__((ext_vector_type(4))) float f32x4;

__device__ __forceinline__ short f2bf(float f) {
  unsigned u = __builtin_bit_cast(unsigned, f);
  u += 0x7FFFu + ((u >> 16) & 1u);
  return (short)(u >> 16);
}
__device__ __forceinline__ bf16x8 lds8(const short* p) {
  return __builtin_bit_cast(bf16x8, *(const s16x8*)p);
}
// async global->LDS, 16B/lane; LDS dest = wave-uniform base + lane*16
__device__ __forceinline__ void gload16(const void* g, void* l) {
  __builtin_amdgcn_global_load_lds(
      (const __attribute__((address_space(1))) void*)g,
      (__attribute__((address_space(3))) void*)l, 16, 0, 0);
}

// ---------------------------------------------------------------------------
// Pass 1: K -> bf16, V -> bf16-transposed, tile-major, chunks pre-permuted in
// the main kernel's XOR-swizzled LDS order (staging becomes a raw byte copy).
//   K tile:  chunk(r in[0,64), cix in[0,16)) = K[kv0+r][cix*8..+8)
//            at chunk slot r*16 + (cix ^ (r&7))
//   Vt tile: chunk(d in[0,128), cix in[0,8)) = V[kv0+cix*8..+8][d]
//            at chunk slot d*8 + (cix ^ (d&7))
// ---------------------------------------------------------------------------
__global__ __launch_bounds__(256)
void fa_convert(const float* __restrict__ K, const float* __restrict__ V,
                char* __restrict__ ws) {
  const int bid = blockIdx.x;
  const int tid = threadIdx.x;
  if (bid < 512) {  // K: bid = b*32 + kt
    const int b = bid >> 5, kt = bid & 31;
    const float* kb = K + (size_t)(b * S_LEN + kt * BN) * DK;
    short* out = (short*)(ws + (size_t)bid * TILE_B);
#pragma unroll
    for (int it = 0; it < 4; ++it) {
      int o = it * 256 + tid;
      int r = o >> 4, cix = o & 15;
      const float* src = kb + r * DK + cix * 8;
      float4 x = *(const float4*)src;
      float4 y = *(const float4*)(src + 4);
      s16x8 f;
      f[0] = f2bf(x.x); f[1] = f2bf(x.y); f[2] = f2bf(x.z); f[3] = f2bf(x.w);
      f[4] = f2bf(y.x); f[5] = f2bf(y.y); f[6] = f2bf(y.z); f[7] = f2bf(y.w);
      int pos = r * 16 + (cix ^ (r & 7));
      *(s16x8*)(out + pos * 8) = f;
    }
  } else {  // V transpose (reads coalesced across d)
    const int vb = bid - 512;
    const int b = vb >> 5, kt = vb & 31;
    const float* vbase = V + (size_t)(b * S_LEN + kt * BN) * DV;
    short* out = (short*)(ws + VWS_OFF + (size_t)vb * TILE_B);
#pragma unroll
    for (int it = 0; it < 4; ++it) {
      int o = it * 256 + tid;
      int d = o & 127, cix = o >> 7;  // adjacent lanes -> adjacent d: coalesced
      s16x8 f;
#pragma unroll
      for (int j = 0; j < 8; ++j)
        f[j] = f2bf(vbase[(cix * 8 + j) * DV + d]);
      int pos = d * 8 + (cix ^ (d & 7));
      *(s16x8*)(out + pos * 8) = f;
    }
  }
}

// ---------------------------------------------------------------------------
// Pass 2: transposed-S flash attention. BM=32 (2 waves / 128 threads) so the
// whole 1024-block grid is co-resident (37.4 KB LDS -> 4 blocks/CU, 8
// waves/CU): chain stalls of one block hide under the other three.
// bid mapping: XCD x = bid&7 gets batches {2x, 2x+1} (2 MB KV working set
// per 4 MB XCD L2); heavy Q-groups first within each XCD (perf heuristic).
// ---------------------------------------------------------------------------
__global__ __launch_bounds__(128)
void fa_main(const float* __restrict__ Q, const char* __restrict__ ws,
             float* __restrict__ Out) {
  __shared__ __align__(16) short lds_k[BN * DK];   // 16384 B, swizzled chunks
  __shared__ __align__(16) short lds_vt[DV * BN];  // 16384 B, swizzled chunks
  __shared__ __align__(16) short lds_p[2 * 16 * LDP];  // 4608 B

  const int bid = blockIdx.x;
  const int x = bid & 7, m = bid >> 3;
  const int b  = (x << 1) | (m >> 6);   // batch: 2 per XCD
  const int tq = 63 - (m & 63);         // Q-group 0..63, heavy first
  const int q0 = tq * 32;
  const int te = tq >> 1;               // last KV tile index
  const int dq = (tq & 1) * 32;         // Q-row offset inside diagonal tile

  const int tid = threadIdx.x;
  const int wv  = tid >> 6, ln = tid & 63;
  const int c   = ln & 15, qd = ln >> 4;
  const int s3  = c & 7;
  const float scale2 = 0.12751741f;     // log2(e)/sqrt(128), folded into Q
  const int qg = q0 + wv * 16 + c;

  // Q fragments, pre-scaled: lane c holds Q[qg][t4*32 + qd*8 + j] * scale2
  bf16x8 qf[4];
  {
    const float* qrow = Q + (size_t)(b * S_LEN + qg) * DK + qd * 8;
#pragma unroll
    for (int t4 = 0; t4 < 4; ++t4) {
      float4 xx = *(const float4*)(qrow + t4 * 32);
      float4 yy = *(const float4*)(qrow + t4 * 32 + 4);
      s16x8 f;
      f[0] = f2bf(xx.x * scale2); f[1] = f2bf(xx.y * scale2);
      f[2] = f2bf(xx.z * scale2); f[3] = f2bf(xx.w * scale2);
      f[4] = f2bf(yy.x * scale2); f[5] = f2bf(yy.y * scale2);
      f[6] = f2bf(yy.z * scale2); f[7] = f2bf(yy.w * scale2);
      qf[t4] = __builtin_bit_cast(bf16x8, f);
    }
  }

  // step-invariant swizzled LDS read offsets (element units)
  int koff[4][4], voff[8][2];
#pragma unroll
  for (int cb = 0; cb < 4; ++cb)
#pragma unroll
    for (int t4 = 0; t4 < 4; ++t4)
      koff[cb][t4] = ((cb * 16 + c) * 16 + ((qd + 4 * t4) ^ s3)) * 8;
#pragma unroll
  for (int cb2 = 0; cb2 < 8; ++cb2)
#pragma unroll
    for (int t2 = 0; t2 < 2; ++t2)
      voff[cb2][t2] = ((cb2 * 16 + c) * 8 + ((qd + 4 * t2) ^ s3)) * 8;

  f32x4 oacc[8];
#pragma unroll
  for (int i = 0; i < 8; ++i) oacc[i] = f32x4{0.f, 0.f, 0.f, 0.f};
  float m_i = -1e30f, l_i = 0.f;

  short* pb = &lds_p[wv * 16 * LDP];
  const char* kg = ws + (size_t)(b * NT) * TILE_B + wv * 8192 + ln * 16;
  const char* vg = ws + VWS_OFF + (size_t)(b * NT) * TILE_B + wv * 8192 + ln * 16;
  char* lk = (char*)lds_k + wv * 8192;
  char* lv = (char*)lds_vt + wv * 8192;

  for (int kt = 0; kt <= te; ++kt) {
    __syncthreads();  // prior step's LDS reads done before restage
#pragma unroll
    for (int i = 0; i < 8; ++i) {
      gload16(kg + i * 1024, lk + i * 1024);
      gload16(vg + i * 1024, lv + i * 1024);
    }
    kg += TILE_B; vg += TILE_B;
    __syncthreads();  // drains vmcnt(0): staged tile visible

    // S^T = K Q^T : lane holds S^T[kv = cb*16+qd*4+r][q = c]
    f32x4 st[4];
#pragma unroll
    for (int cb = 0; cb < 4; ++cb) {
      f32x4 acc = f32x4{0.f, 0.f, 0.f, 0.f};
#pragma unroll
      for (int t4 = 0; t4 < 4; ++t4)
        acc = __builtin_amdgcn_mfma_f32_16x16x32_bf16(
            lds8(&lds_k[koff[cb][t4]]), qf[t4], acc, 0, 0, 0);
      st[cb] = acc;
    }

    // causal mask, diagonal tile only
    if (kt == te) {
#pragma unroll
      for (int cb = 0; cb < 4; ++cb)
#pragma unroll
        for (int r = 0; r < 4; ++r)
          if (cb * 16 + qd * 4 + r > dq + wv * 16 + c) st[cb][r] = -1e30f;
    }

    // online softmax over kv (16 regs + lanes differing in qd bits)
    float tmax = -1e30f;
#pragma unroll
    for (int cb = 0; cb < 4; ++cb)
#pragma unroll
      for (int r = 0; r < 4; ++r) tmax = fmaxf(tmax, st[cb][r]);
    tmax = fmaxf(tmax, __shfl_xor(tmax, 16));
    tmax = fmaxf(tmax, __shfl_xor(tmax, 32));

    float mn = fmaxf(m_i, tmax);
    float al = __builtin_amdgcn_exp2f(m_i - mn);
    m_i = mn;
    float tsum = 0.f;
#pragma unroll
    for (int cb = 0; cb < 4; ++cb) {
      s16x4 pk;
#pragma unroll
      for (int r = 0; r < 4; ++r) {
        float p = __builtin_amdgcn_exp2f(st[cb][r] - m_i);
        tsum += p;
        pk[r] = f2bf(p);
      }
      *(s16x4*)&pb[c * LDP + cb * 16 + qd * 4] = pk;  // P[q=c][kv], b64
    }
    tsum += __shfl_xor(tsum, 16);
    tsum += __shfl_xor(tsum, 32);
    l_i = l_i * al + tsum;
#pragma unroll
    for (int i = 0; i < 8; ++i)
#pragma unroll
      for (int r = 0; r < 4; ++r) oacc[i][r] *= al;

    // O^T += V^T P^T  (P wave-private: wave-lockstep + lgkmcnt suffice)
#pragma unroll
    for (int t2 = 0; t2 < 2; ++t2) {
      bf16x8 pf = lds8(&pb[c * LDP + t2 * 32 + qd * 8]);
#pragma unroll
      for (int cb2 = 0; cb2 < 8; ++cb2) {
        bf16x8 vf = lds8(&lds_vt[voff[cb2][t2]]);
        oacc[cb2] = __builtin_amdgcn_mfma_f32_16x16x32_bf16(vf, pf, oacc[cb2], 0, 0, 0);
      }
    }
  }

  // epilogue: normalize, store fp32 (lane holds O[q=c][d=cb2*16+qd*4+r])
  float inv = 1.0f / l_i;
  float* ob = Out + (size_t)(b * S_LEN + qg) * DV;
#pragma unroll
  for (int cb2 = 0; cb2 < 8; ++cb2) {
    f32x4 v = oacc[cb2] * inv;
    *(f32x4*)(ob + cb2 * 16 + qd * 4) = v;
  }
}

// ---------------------------------------------------------------------------
// Fallback (ws too small): single-pass kernel with in-kernel convert (R2).
// ---------------------------------------------------------------------------
__global__ __launch_bounds__(256)
void fa_fallback(const float* __restrict__ Q, const float* __restrict__ K,
                 const float* __restrict__ V, float* __restrict__ Out) {
  __shared__ __align__(16) short lds_k[BN * 136];
  __shared__ __align__(16) short lds_vt[DV * 72];
  __shared__ __align__(16) short lds_p[4 * 16 * LDP];

  const int bid = blockIdx.x;
  const int b = bid >> 5, t = bid & 31;
  const int q0 = t * 64;
  const int tid = threadIdx.x;
  const int wv = tid >> 6, ln = tid & 63;
  const int c = ln & 15, qd = ln >> 4;
  const float scale2 = 0.12751741f;
  const int qg = q0 + wv * 16 + c;

  bf16x8 qf[4];
  {
    const float* qrow = Q + (size_t)(b * S_LEN + qg) * DK + qd * 8;
#pragma unroll
    for (int t4 = 0; t4 < 4; ++t4) {
      float4 xx = *(const float4*)(qrow + t4 * 32);
      float4 yy = *(const float4*)(qrow + t4 * 32 + 4);
      s16x8 f;
      f[0] = f2bf(xx.x * scale2); f[1] = f2bf(xx.y * scale2);
      f[2] = f2bf(xx.z * scale2); f[3] = f2bf(xx.w * scale2);
      f[4] = f2bf(yy.x * scale2); f[5] = f2bf(yy.y * scale2);
      f[6] = f2bf(yy.z * scale2); f[7] = f2bf(yy.w * scale2);
      qf[t4] = __builtin_bit_cast(bf16x8, f);
    }
  }
  f32x4 oacc[8];
#pragma unroll
  for (int i = 0; i < 8; ++i) oacc[i] = f32x4{0.f, 0.f, 0.f, 0.f};
  float m_i = -1e30f, l_i = 0.f;
  const float* kbb = K + (size_t)b * S_LEN * DK;
  const float* vbb = V + (size_t)b * S_LEN * DV;
  short* pb = &lds_p[wv * 16 * LDP];

  for (int kt = 0; kt <= t; ++kt) {
    const int kv0 = kt * BN;
    __syncthreads();
    {
      const float* kb = kbb + (size_t)kv0 * DK;
#pragma unroll
      for (int it = 0; it < 8; ++it) {
        int flat = it * 256 + tid;
        int r = flat >> 5, d4 = flat & 31;
        float4 xx = *(const float4*)(kb + r * DK + d4 * 4);
        s16x4 s;
        s[0] = f2bf(xx.x); s[1] = f2bf(xx.y); s[2] = f2bf(xx.z); s[3] = f2bf(xx.w);
        *(s16x4*)&lds_k[r * 136 + d4 * 4] = s;
      }
      const float* vb = vbb + (size_t)kv0 * DV;
#pragma unroll
      for (int it = 0; it < 8; ++it) {
        int flat = it * 256 + tid;
        int d = flat & 127, r0 = (flat >> 7) << 2;
        s16x4 s;
        s[0] = f2bf(vb[(r0 + 0) * DV + d]);
        s[1] = f2bf(vb[(r0 + 1) * DV + d]);
        s[2] = f2bf(vb[(r0 + 2) * DV + d]);
        s[3] = f2bf(vb[(r0 + 3) * DV + d]);
        *(s16x4*)&lds_vt[d * 72 + r0] = s;
      }
    }
    __syncthreads();
    f32x4 st[4];
#pragma unroll
    for (int cb = 0; cb < 4; ++cb) {
      f32x4 acc = f32x4{0.f, 0.f, 0.f, 0.f};
      const short* kr = &lds_k[(cb * 16 + c) * 136 + qd * 8];
#pragma unroll
      for (int t4 = 0; t4 < 4; ++t4)
        acc = __builtin_amdgcn_mfma_f32_16x16x32_bf16(lds8(kr + t4 * 32), qf[t4], acc, 0, 0, 0);
      st[cb] = acc;
    }
    if (kt == t) {
#pragma unroll
      for (int cb = 0; cb < 4; ++cb)
#pragma unroll
        for (int r = 0; r < 4; ++r)
          if (cb * 16 + qd * 4 + r > wv * 16 + c) st[cb][r] = -1e30f;
    }
    float tmax = -1e30f;
#pragma unroll
    for (int cb = 0; cb < 4; ++cb)
#pragma unroll
      for (int r = 0; r < 4; ++r) tmax = fmaxf(tmax, st[cb][r]);
    tmax = fmaxf(tmax, __shfl_xor(tmax, 16));
    tmax = fmaxf(tmax, __shfl_xor(tmax, 32));
    float mn = fmaxf(m_i, tmax);
    float al = __builtin_amdgcn_exp2f(m_i - mn);
    m_i = mn;
    float tsum = 0.f;
#pragma unroll
    for (int cb = 0; cb < 4; ++cb) {
      s16x4 pk;
#pragma unroll
      for (int r = 0; r < 4; ++r) {
        float p = __builtin_amdgcn_exp2f(st[cb][r] - m_i);
        tsum += p;
        pk[r] = f2bf(p);
      }
      *(s16x4*)&pb[c * LDP + cb * 16 + qd * 4] = pk;
    }
    tsum += __shfl_xor(tsum, 16);
    tsum += __shfl_xor(tsum, 32);
    l_i = l_i * al + tsum;
#pragma unroll
    for (int i = 0; i < 8; ++i)
#pragma unroll
      for (int r = 0; r < 4; ++r) oacc[i][r] *= al;
#pragma unroll
    for (int t2 = 0; t2 < 2; ++t2) {
      bf16x8 pf = lds8(&pb[c * LDP + t2 * 32 + qd * 8]);
#pragma unroll
      for (int cb2 = 0; cb2 < 8; ++cb2) {
        bf16x8 vf = lds8(&lds_vt[(cb2 * 16 + c) * 72 + t2 * 32 + qd * 8]);
        oacc[cb2] = __builtin_amdgcn_mfma_f32_16x16x32_bf16(vf, pf, oacc[cb2], 0, 0, 0);
      }
    }
  }
  float inv = 1.0f / l_i;
  float* ob = Out + (size_t)(b * S_LEN + qg) * DV;
#pragma unroll
  for (int cb2 = 0; cb2 < 8; ++cb2) {
    f32x4 v = oacc[cb2] * inv;
    *(f32x4*)(ob + cb2 * 16 + qd * 4) = v;
  }
}

extern "C" void kernel_launch(void* const* d_in, const int* in_sizes, int n_in,
                              void* d_out, int out_size, void* d_ws, size_t ws_size,
                              hipStream_t stream) {
  (void)in_sizes; (void)n_in; (void)out_size;
  const float* Q = (const float*)d_in[0];
  const float* K = (const float*)d_in[1];
  const float* V = (const float*)d_in[2];
  float* O = (float*)d_out;
  if (ws_size >= WS_NEED) {
    fa_convert<<<dim3(1024), dim3(256), 0, stream>>>(K, V, (char*)d_ws);
    fa_main<<<dim3(1024), dim3(128), 0, stream>>>(Q, (const char*)d_ws, O);
  } else {
    fa_fallback<<<dim3(512), dim3(256), 0, stream>>>(Q, K, V, O);
  }
}

// Round 5
// 150.318 us; speedup vs baseline: 1.0495x; 1.0495x over previous
//
#include <hip/hip_runtime.h>
#include <hip/hip_bf16.h>

#define S_LEN 2048
#define DK 128
#define DV 128
#define BN 64     // KV rows per tile
#define NT 32     // KV tiles per batch
#define LDP 72    // LDS P row stride (bf16)
#define TILE_B 16384                        // bytes per staged tile (64x128 bf16)
#define VWS_OFF ((size_t)16 * NT * TILE_B)  // 8.39 MB
#define WS_NEED ((size_t)2 * 16 * NT * TILE_B)

typedef __attribute__((ext_vector_type(8))) short s16x8;
typedef __attribute__((ext_vector_type(4))) short s16x4;
typedef __attribute__((ext_vector_type(8))) __bf16 bf16x8;
typedef __attribute__((ext_vector_type(4))) float f32x4;

__device__ __forceinline__ short f2bf(float f) {
  unsigned u = __builtin_bit_cast(unsigned, f);
  u += 0x7FFFu + ((u >> 16) & 1u);
  return (short)(u >> 16);
}
__device__ __forceinline__ bf16x8 lds8(const short* p) {
  return __builtin_bit_cast(bf16x8, *(const s16x8*)p);
}
// async global->LDS, 16B/lane; LDS dest = wave-uniform base + lane*16
__device__ __forceinline__ void gload16(const void* g, void* l) {
  __builtin_amdgcn_global_load_lds(
      (const __attribute__((address_space(1))) void*)g,
      (__attribute__((address_space(3))) void*)l, 16, 0, 0);
}

// ---------------------------------------------------------------------------
// Pass 1: K -> bf16, V -> bf16-transposed, tile-major, chunks pre-permuted in
// the main kernel's XOR-swizzled LDS order (staging becomes a raw byte copy).
//   K tile:  chunk(r in[0,64), cix in[0,16)) = K[kv0+r][cix*8..+8)
//            at chunk slot r*16 + (cix ^ (r&7))
//   Vt tile: chunk(d in[0,128), cix in[0,8)) = V[kv0+cix*8..+8][d]
//            at chunk slot d*8 + (cix ^ (d&7))
// ---------------------------------------------------------------------------
__global__ __launch_bounds__(256)
void fa_convert(const float* __restrict__ K, const float* __restrict__ V,
                char* __restrict__ ws) {
  const int bid = blockIdx.x;
  const int tid = threadIdx.x;
  if (bid < 512) {  // K: bid = b*32 + kt
    const int b = bid >> 5, kt = bid & 31;
    const float* kb = K + (size_t)(b * S_LEN + kt * BN) * DK;
    short* out = (short*)(ws + (size_t)bid * TILE_B);
#pragma unroll
    for (int it = 0; it < 4; ++it) {
      int o = it * 256 + tid;
      int r = o >> 4, cix = o & 15;
      const float* src = kb + r * DK + cix * 8;
      float4 x = *(const float4*)src;
      float4 y = *(const float4*)(src + 4);
      s16x8 f;
      f[0] = f2bf(x.x); f[1] = f2bf(x.y); f[2] = f2bf(x.z); f[3] = f2bf(x.w);
      f[4] = f2bf(y.x); f[5] = f2bf(y.y); f[6] = f2bf(y.z); f[7] = f2bf(y.w);
      int pos = r * 16 + (cix ^ (r & 7));
      *(s16x8*)(out + pos * 8) = f;
    }
  } else {  // V transpose (reads coalesced across d)
    const int vb = bid - 512;
    const int b = vb >> 5, kt = vb & 31;
    const float* vbase = V + (size_t)(b * S_LEN + kt * BN) * DV;
    short* out = (short*)(ws + VWS_OFF + (size_t)vb * TILE_B);
#pragma unroll
    for (int it = 0; it < 4; ++it) {
      int o = it * 256 + tid;
      int d = o & 127, cix = o >> 7;  // adjacent lanes -> adjacent d: coalesced
      s16x8 f;
#pragma unroll
      for (int j = 0; j < 8; ++j)
        f[j] = f2bf(vbase[(cix * 8 + j) * DV + d]);
      int pos = d * 8 + (cix ^ (d & 7));
      *(s16x8*)(out + pos * 8) = f;
    }
  }
}

// ---------------------------------------------------------------------------
// Pass 2: transposed-S flash attention, BM=64 (4 waves), double-buffered K/Vt
// staging with ONE barrier per KV step (load latency hidden behind compute).
// Pairing: bids j and j+256 land on the same CU (round-robin over 256 CUs);
// t = 16+i vs 15-i with the same batch -> every CU gets exactly 33 KV-steps
// and both its blocks share one batch's K/V in L2.
// LDS 74752 B -> 2 blocks/CU (8 waves/CU).
// ---------------------------------------------------------------------------
__global__ __launch_bounds__(256)
void fa_main(const float* __restrict__ Q, const char* __restrict__ ws,
             float* __restrict__ Out) {
  __shared__ __align__(16) short lds_k[2 * BN * DK];   // 2 x 16384 B, swizzled
  __shared__ __align__(16) short lds_vt[2 * DV * BN];  // 2 x 16384 B, swizzled
  __shared__ __align__(16) short lds_p[4 * 16 * LDP];  // 9216 B

  const int bid = blockIdx.x;
  const int i = bid & 15;
  const int b = (bid >> 4) & 15;
  const int t = (bid < 256) ? (16 + i) : (15 - i);
  const int q0 = t * 64;

  const int tid = threadIdx.x;
  const int wv  = tid >> 6, ln = tid & 63;
  const int c   = ln & 15, qd = ln >> 4;
  const int s3  = c & 7;
  const float scale2 = 0.12751741f;     // log2(e)/sqrt(128), folded into Q
  const int qg = q0 + wv * 16 + c;

  // prologue stage: tile 0 -> buffer 0 (this wave's quarter of K and Vt)
  const char* kg = ws + (size_t)(b * NT) * TILE_B + wv * 4096 + ln * 16;
  const char* vg = ws + VWS_OFF + (size_t)(b * NT) * TILE_B + wv * 4096 + ln * 16;
  {
    char* lk = (char*)lds_k + wv * 4096;
    char* lv = (char*)lds_vt + wv * 4096;
#pragma unroll
    for (int u = 0; u < 4; ++u) {
      gload16(kg + u * 1024, lk + u * 1024);
      gload16(vg + u * 1024, lv + u * 1024);
    }
    kg += TILE_B; vg += TILE_B;
  }

  // Q fragments, pre-scaled: lane c holds Q[qg][t4*32 + qd*8 + j] * scale2
  bf16x8 qf[4];
  {
    const float* qrow = Q + (size_t)(b * S_LEN + qg) * DK + qd * 8;
#pragma unroll
    for (int t4 = 0; t4 < 4; ++t4) {
      float4 xx = *(const float4*)(qrow + t4 * 32);
      float4 yy = *(const float4*)(qrow + t4 * 32 + 4);
      s16x8 f;
      f[0] = f2bf(xx.x * scale2); f[1] = f2bf(xx.y * scale2);
      f[2] = f2bf(xx.z * scale2); f[3] = f2bf(xx.w * scale2);
      f[4] = f2bf(yy.x * scale2); f[5] = f2bf(yy.y * scale2);
      f[6] = f2bf(yy.z * scale2); f[7] = f2bf(yy.w * scale2);
      qf[t4] = __builtin_bit_cast(bf16x8, f);
    }
  }

  // step-invariant swizzled LDS read offsets (element units, buffer 0)
  int koff[4][4], voff[8][2];
#pragma unroll
  for (int cb = 0; cb < 4; ++cb)
#pragma unroll
    for (int t4 = 0; t4 < 4; ++t4)
      koff[cb][t4] = ((cb * 16 + c) * 16 + ((qd + 4 * t4) ^ s3)) * 8;
#pragma unroll
  for (int cb2 = 0; cb2 < 8; ++cb2)
#pragma unroll
    for (int t2 = 0; t2 < 2; ++t2)
      voff[cb2][t2] = ((cb2 * 16 + c) * 8 + ((qd + 4 * t2) ^ s3)) * 8;

  f32x4 oacc[8];
#pragma unroll
  for (int u = 0; u < 8; ++u) oacc[u] = f32x4{0.f, 0.f, 0.f, 0.f};
  float m_i = -1e30f, l_i = 0.f;
  short* pb = &lds_p[wv * 16 * LDP];

  for (int kt = 0; kt <= t; ++kt) {
    const int cur = kt & 1;
    // Barrier: (a) every wave's stage of tile kt (vmcnt) drained -> buf(cur)
    // fully staged; (b) all reads of buf(1-cur) from step kt-1 done -> safe
    // to overwrite it with tile kt+1.
    __syncthreads();

    if (kt < t) {  // stage tile kt+1 -> buf(1-cur); latency hides under compute
      char* lk = (char*)lds_k + (cur ^ 1) * 16384 + wv * 4096;
      char* lv = (char*)lds_vt + (cur ^ 1) * 16384 + wv * 4096;
#pragma unroll
      for (int u = 0; u < 4; ++u) {
        gload16(kg + u * 1024, lk + u * 1024);
        gload16(vg + u * 1024, lv + u * 1024);
      }
      kg += TILE_B; vg += TILE_B;
    }
    const int bo = cur * 8192;  // element offset of current buffer

    // S^T = K Q^T : lane holds S^T[kv = cb*16+qd*4+r][q = c]
    f32x4 st[4];
#pragma unroll
    for (int cb = 0; cb < 4; ++cb) {
      f32x4 acc = f32x4{0.f, 0.f, 0.f, 0.f};
#pragma unroll
      for (int t4 = 0; t4 < 4; ++t4)
        acc = __builtin_amdgcn_mfma_f32_16x16x32_bf16(
            lds8(&lds_k[bo + koff[cb][t4]]), qf[t4], acc, 0, 0, 0);
      st[cb] = acc;
    }

    // causal mask, diagonal tile only
    if (kt == t) {
#pragma unroll
      for (int cb = 0; cb < 4; ++cb)
#pragma unroll
        for (int r = 0; r < 4; ++r)
          if (cb * 16 + qd * 4 + r > wv * 16 + c) st[cb][r] = -1e30f;
    }

    // online softmax over kv (16 regs + lanes differing in qd bits)
    float tmax = -1e30f;
#pragma unroll
    for (int cb = 0; cb < 4; ++cb)
#pragma unroll
      for (int r = 0; r < 4; ++r) tmax = fmaxf(tmax, st[cb][r]);
    tmax = fmaxf(tmax, __shfl_xor(tmax, 16));
    tmax = fmaxf(tmax, __shfl_xor(tmax, 32));

    float mn = fmaxf(m_i, tmax);
    float al = __builtin_amdgcn_exp2f(m_i - mn);
    m_i = mn;
    float tsum = 0.f;
#pragma unroll
    for (int cb = 0; cb < 4; ++cb) {
      s16x4 pk;
#pragma unroll
      for (int r = 0; r < 4; ++r) {
        float p = __builtin_amdgcn_exp2f(st[cb][r] - m_i);
        tsum += p;
        pk[r] = f2bf(p);
      }
      *(s16x4*)&pb[c * LDP + cb * 16 + qd * 4] = pk;  // P[q=c][kv], b64
    }
    tsum += __shfl_xor(tsum, 16);
    tsum += __shfl_xor(tsum, 32);
    l_i = l_i * al + tsum;
#pragma unroll
    for (int u = 0; u < 8; ++u)
#pragma unroll
      for (int r = 0; r < 4; ++r) oacc[u][r] *= al;

    // O^T += V^T P^T  (P wave-private: wave-lockstep + lgkmcnt suffice)
#pragma unroll
    for (int t2 = 0; t2 < 2; ++t2) {
      bf16x8 pf = lds8(&pb[c * LDP + t2 * 32 + qd * 8]);
#pragma unroll
      for (int cb2 = 0; cb2 < 8; ++cb2) {
        bf16x8 vf = lds8(&lds_vt[bo + voff[cb2][t2]]);
        oacc[cb2] = __builtin_amdgcn_mfma_f32_16x16x32_bf16(vf, pf, oacc[cb2], 0, 0, 0);
      }
    }
  }

  // epilogue: normalize, store fp32 (lane holds O[q=c][d=cb2*16+qd*4+r])
  float inv = 1.0f / l_i;
  float* ob = Out + (size_t)(b * S_LEN + qg) * DV;
#pragma unroll
  for (int cb2 = 0; cb2 < 8; ++cb2) {
    f32x4 v = oacc[cb2] * inv;
    *(f32x4*)(ob + cb2 * 16 + qd * 4) = v;
  }
}

// ---------------------------------------------------------------------------
// Fallback (ws too small): single-pass kernel with in-kernel convert (R2).
// ---------------------------------------------------------------------------
__global__ __launch_bounds__(256)
void fa_fallback(const float* __restrict__ Q, const float* __restrict__ K,
                 const float* __restrict__ V, float* __restrict__ Out) {
  __shared__ __align__(16) short lds_k[BN * 136];
  __shared__ __align__(16) short lds_vt[DV * 72];
  __shared__ __align__(16) short lds_p[4 * 16 * LDP];

  const int bid = blockIdx.x;
  const int b = bid >> 5, t = bid & 31;
  const int q0 = t * 64;
  const int tid = threadIdx.x;
  const int wv = tid >> 6, ln = tid & 63;
  const int c = ln & 15, qd = ln >> 4;
  const float scale2 = 0.12751741f;
  const int qg = q0 + wv * 16 + c;

  bf16x8 qf[4];
  {
    const float* qrow = Q + (size_t)(b * S_LEN + qg) * DK + qd * 8;
#pragma unroll
    for (int t4 = 0; t4 < 4; ++t4) {
      float4 xx = *(const float4*)(qrow + t4 * 32);
      float4 yy = *(const float4*)(qrow + t4 * 32 + 4);
      s16x8 f;
      f[0] = f2bf(xx.x * scale2); f[1] = f2bf(xx.y * scale2);
      f[2] = f2bf(xx.z * scale2); f[3] = f2bf(xx.w * scale2);
      f[4] = f2bf(yy.x * scale2); f[5] = f2bf(yy.y * scale2);
      f[6] = f2bf(yy.z * scale2); f[7] = f2bf(yy.w * scale2);
      qf[t4] = __builtin_bit_cast(bf16x8, f);
    }
  }
  f32x4 oacc[8];
#pragma unroll
  for (int u = 0; u < 8; ++u) oacc[u] = f32x4{0.f, 0.f, 0.f, 0.f};
  float m_i = -1e30f, l_i = 0.f;
  const float* kbb = K + (size_t)b * S_LEN * DK;
  const float* vbb = V + (size_t)b * S_LEN * DV;
  short* pb = &lds_p[wv * 16 * LDP];

  for (int kt = 0; kt <= t; ++kt) {
    const int kv0 = kt * BN;
    __syncthreads();
    {
      const float* kb = kbb + (size_t)kv0 * DK;
#pragma unroll
      for (int it = 0; it < 8; ++it) {
        int flat = it * 256 + tid;
        int r = flat >> 5, d4 = flat & 31;
        float4 xx = *(const float4*)(kb + r * DK + d4 * 4);
        s16x4 s;
        s[0] = f2bf(xx.x); s[1] = f2bf(xx.y); s[2] = f2bf(xx.z); s[3] = f2bf(xx.w);
        *(s16x4*)&lds_k[r * 136 + d4 * 4] = s;
      }
      const float* vb = vbb + (size_t)kv0 * DV;
#pragma unroll
      for (int it = 0; it < 8; ++it) {
        int flat = it * 256 + tid;
        int d = flat & 127, r0 = (flat >> 7) << 2;
        s16x4 s;
        s[0] = f2bf(vb[(r0 + 0) * DV + d]);
        s[1] = f2bf(vb[(r0 + 1) * DV + d]);
        s[2] = f2bf(vb[(r0 + 2) * DV + d]);
        s[3] = f2bf(vb[(r0 + 3) * DV + d]);
        *(s16x4*)&lds_vt[d * 72 + r0] = s;
      }
    }
    __syncthreads();
    f32x4 st[4];
#pragma unroll
    for (int cb = 0; cb < 4; ++cb) {
      f32x4 acc = f32x4{0.f, 0.f, 0.f, 0.f};
      const short* kr = &lds_k[(cb * 16 + c) * 136 + qd * 8];
#pragma unroll
      for (int t4 = 0; t4 < 4; ++t4)
        acc = __builtin_amdgcn_mfma_f32_16x16x32_bf16(lds8(kr + t4 * 32), qf[t4], acc, 0, 0, 0);
      st[cb] = acc;
    }
    if (kt == t) {
#pragma unroll
      for (int cb = 0; cb < 4; ++cb)
#pragma unroll
        for (int r = 0; r < 4; ++r)
          if (cb * 16 + qd * 4 + r > wv * 16 + c) st[cb][r] = -1e30f;
    }
    float tmax = -1e30f;
#pragma unroll
    for (int cb = 0; cb < 4; ++cb)
#pragma unroll
      for (int r = 0; r < 4; ++r) tmax = fmaxf(tmax, st[cb][r]);
    tmax = fmaxf(tmax, __shfl_xor(tmax, 16));
    tmax = fmaxf(tmax, __shfl_xor(tmax, 32));
    float mn = fmaxf(m_i, tmax);
    float al = __builtin_amdgcn_exp2f(m_i - mn);
    m_i = mn;
    float tsum = 0.f;
#pragma unroll
    for (int cb = 0; cb < 4; ++cb) {
      s16x4 pk;
#pragma unroll
      for (int r = 0; r < 4; ++r) {
        float p = __builtin_amdgcn_exp2f(st[cb][r] - m_i);
        tsum += p;
        pk[r] = f2bf(p);
      }
      *(s16x4*)&pb[c * LDP + cb * 16 + qd * 4] = pk;
    }
    tsum += __shfl_xor(tsum, 16);
    tsum += __shfl_xor(tsum, 32);
    l_i = l_i * al + tsum;
#pragma unroll
    for (int u = 0; u < 8; ++u)
#pragma unroll
      for (int r = 0; r < 4; ++r) oacc[u][r] *= al;
#pragma unroll
    for (int t2 = 0; t2 < 2; ++t2) {
      bf16x8 pf = lds8(&pb[c * LDP + t2 * 32 + qd * 8]);
#pragma unroll
      for (int cb2 = 0; cb2 < 8; ++cb2) {
        bf16x8 vf = lds8(&lds_vt[(cb2 * 16 + c) * 72 + t2 * 32 + qd * 8]);
        oacc[cb2] = __builtin_amdgcn_mfma_f32_16x16x32_bf16(vf, pf, oacc[cb2], 0, 0, 0);
      }
    }
  }
  float inv = 1.0f / l_i;
  float* ob = Out + (size_t)(b * S_LEN + qg) * DV;
#pragma unroll
  for (int cb2 = 0; cb2 < 8; ++cb2) {
    f32x4 v = oacc[cb2] * inv;
    *(f32x4*)(ob + cb2 * 16 + qd * 4) = v;
  }
}

extern "C" void kernel_launch(void* const* d_in, const int* in_sizes, int n_in,
                              void* d_out, int out_size, void* d_ws, size_t ws_size,
                              hipStream_t stream) {
  (void)in_sizes; (void)n_in; (void)out_size;
  const float* Q = (const float*)d_in[0];
  const float* K = (const float*)d_in[1];
  const float* V = (const float*)d_in[2];
  float* O = (float*)d_out;
  if (ws_size >= WS_NEED) {
    fa_convert<<<dim3(1024), dim3(256), 0, stream>>>(K, V, (char*)d_ws);
    fa_main<<<dim3(512), dim3(256), 0, stream>>>(Q, (const char*)d_ws, O);
  } else {
    fa_fallback<<<dim3(512), dim3(256), 0, stream>>>(Q, K, V, O);
  }
}